// Round 4
// baseline (6673.636 us; speedup 1.0000x reference)
//
#include <hip/hip_runtime.h>

#define N_USERS 1000000
#define NEDGE   32000000
#define OUT_F   64
#define BN_EPS  1e-5f

// Destination binning geometry.
// S_BUCKET=4096 is the max where meta packs: dst_local(12b)<<20 | src(20b).
#define SBITS     12
#define S_BUCKET  4096                     // nodes per bucket
#define NB        245                      // ceil(N_USERS / S_BUCKET)
// CAP: mean 130612, sigma ~361; slack 6284 ~ 17 sigma. NB*CAP*8 = 268.3MB must
// fit in d_out (268.43MB) because the sorted record array lives there.
#define CAP       136896
#define SCAT_BLOCKS 1024
#define CHUNK     (NEDGE / SCAT_BLOCKS)    // 31250
#define SORT_BLOCKS 64                     // few blocks: keeps sort's write-combine set in L2

typedef unsigned int uint4v __attribute__((ext_vector_type(4)));  // nontemporal-loadable

// ---------------- binned path ----------------

__global__ void init_cursors(unsigned* __restrict__ cursors) {
    int i = blockIdx.x * blockDim.x + threadIdx.x;
    if (i < NB) cursors[i] = (unsigned)i * CAP;
}

// Partition edges by destination bucket. Per block: LDS histogram of its chunk,
// one global atomicAdd per non-empty bucket to reserve a contiguous range, then
// scatter packed 8B records (meta = dst_local<<20 | src, weight bits).
__global__ __launch_bounds__(256) void scatter_bin(
    const int* __restrict__ src, const int* __restrict__ dst,
    const float* __restrict__ ew, uint2* __restrict__ rec,
    unsigned* __restrict__ cursors) {
    __shared__ unsigned cnt[NB];
    __shared__ unsigned base[NB];
    int tid = threadIdx.x;
    int start = blockIdx.x * CHUNK;
    int end = start + CHUNK;

    for (int i = tid; i < NB; i += 256) cnt[i] = 0;
    __syncthreads();
    for (int i = start + tid; i < end; i += 256) {
        int d = __builtin_nontemporal_load(&dst[i]);
        atomicAdd(&cnt[d >> SBITS], 1u);
    }
    __syncthreads();
    for (int i = tid; i < NB; i += 256) {
        unsigned c = cnt[i];
        base[i] = c ? atomicAdd(&cursors[i], c) : 0u;
    }
    __syncthreads();
    for (int i = tid; i < NB; i += 256) cnt[i] = 0;
    __syncthreads();
    for (int i = start + tid; i < end; i += 256) {
        int d = __builtin_nontemporal_load(&dst[i]);
        int s = __builtin_nontemporal_load(&src[i]);
        float w = __builtin_nontemporal_load(&ew[i]);
        int b = d >> SBITS;
        unsigned p = base[b] + atomicAdd(&cnt[b], 1u);
        unsigned meta = ((unsigned)(d & (S_BUCKET - 1)) << 20) | (unsigned)s;
        rec[p] = make_uint2(meta, __float_as_uint(w));
    }
}

// Counting-sort each bucket's records by exact dst_local (4096 keys), writing
// (src, weight) records grouped by destination into rec2 (lives in d_out), and
// emitting per-node rowstart (global record index) + rowcnt. Done ONCE; the
// 4 hop passes then need no atomics at all. SORT_BLOCKS=64 bounds the
// scattered-write working set (8 blocks/XCD * 4096 lines * 64B = 2MB < L2).
__global__ __launch_bounds__(256) void sort_bucket(
    const uint2* __restrict__ rec, const unsigned* __restrict__ cursors,
    uint2* __restrict__ rec2, unsigned* __restrict__ rowstart,
    unsigned char* __restrict__ rowcnt) {
    __shared__ unsigned offs[S_BUCKET];   // histogram -> exclusive offsets
    __shared__ unsigned cnt2[S_BUCKET];
    __shared__ unsigned chunkT[256];
    int tid = threadIdx.x;

    for (int b = blockIdx.x; b < NB; b += SORT_BLOCKS) {
        for (int k = tid; k < S_BUCKET; k += 256) { offs[k] = 0; cnt2[k] = 0; }
        __syncthreads();

        unsigned start = (unsigned)b * CAP;          // even -> 16B-aligned
        unsigned n = cursors[b] - start;
        const uint2* bp = rec + start;

        // pass A: histogram of dst_local
        unsigned i = 2u * (unsigned)tid;
        for (; i + 2u <= n; i += 512u) {
            uint4v r = __builtin_nontemporal_load(reinterpret_cast<const uint4v*>(bp + i));
            atomicAdd(&offs[r.x >> 20], 1u);
            atomicAdd(&offs[r.z >> 20], 1u);
        }
        if (i < n) {                                  // odd tail (exactly one thread)
            uint2 r = bp[i];
            atomicAdd(&offs[r.x >> 20], 1u);
        }
        __syncthreads();

        // per-node counts (before in-place scan destroys them)
        int nb0 = b << SBITS;
        for (int k = tid; k < S_BUCKET; k += 256)
            rowcnt[nb0 + k] = (unsigned char)offs[k];   // Poisson(32): >255 impossible
        __syncthreads();

        // exclusive prefix sum over offs[4096]: 16 cells/thread + serial chunk scan
        {
            int base = tid * 16;
            unsigned run = 0;
            for (int k = 0; k < 16; ++k) { unsigned v = offs[base + k]; offs[base + k] = run; run += v; }
            chunkT[tid] = run;
        }
        __syncthreads();
        if (tid == 0) {
            unsigned run = 0;
            for (int t = 0; t < 256; ++t) { unsigned v = chunkT[t]; chunkT[t] = run; run += v; }
        }
        __syncthreads();
        {
            int base = tid * 16;
            unsigned add = chunkT[tid];
            for (int k = 0; k < 16; ++k) offs[base + k] += add;
        }
        __syncthreads();

        for (int k = tid; k < S_BUCKET; k += 256)
            rowstart[nb0 + k] = start + offs[k];

        // pass B: scatter records to exact sorted positions (src, weight)
        i = 2u * (unsigned)tid;
        for (; i + 2u <= n; i += 512u) {
            uint4v r = __builtin_nontemporal_load(reinterpret_cast<const uint4v*>(bp + i));
            unsigned d0 = r.x >> 20, d1 = r.z >> 20;
            unsigned p0 = offs[d0] + atomicAdd(&cnt2[d0], 1u);
            unsigned p1 = offs[d1] + atomicAdd(&cnt2[d1], 1u);
            rec2[start + p0] = make_uint2(r.x & 0xFFFFFu, r.y);
            rec2[start + p1] = make_uint2(r.z & 0xFFFFFu, r.w);
        }
        if (i < n) {
            uint2 r = bp[i];
            unsigned d0 = r.x >> 20;
            unsigned p0 = offs[d0] + atomicAdd(&cnt2[d0], 1u);
            rec2[start + p0] = make_uint2(r.x & 0xFFFFFu, r.y);
        }
        __syncthreads();   // before next bucket re-zeroes offs/cnt2
    }
}

// CSR hop: one thread per destination node, register accumulation, no atomics.
// Records are contiguous per node; read 4/iter (two 16B nt loads) for MLP.
__global__ __launch_bounds__(256) void hop_csr(
    const uint2* __restrict__ rec2, const unsigned* __restrict__ rowstart,
    const unsigned char* __restrict__ rowcnt, const float* __restrict__ cur,
    float* __restrict__ nxt) {
    int n = blockIdx.x * 256 + threadIdx.x;
    if (n >= N_USERS) return;
    unsigned s = rowstart[n];
    int c = rowcnt[n];
    float sum = 0.0f;
    if ((s & 1u) && c > 0) {                       // align to 16B
        uint2 r = rec2[s];
        sum += cur[r.x] * __uint_as_float(r.y);
        ++s; --c;
    }
    for (; c >= 4; c -= 4, s += 4) {
        uint4v r0 = __builtin_nontemporal_load(reinterpret_cast<const uint4v*>(rec2 + s));
        uint4v r1 = __builtin_nontemporal_load(reinterpret_cast<const uint4v*>(rec2 + s + 2));
        float c0 = cur[r0.x], c1 = cur[r0.z], c2 = cur[r1.x], c3 = cur[r1.z];
        sum += c0 * __uint_as_float(r0.y);
        sum += c1 * __uint_as_float(r0.w);
        sum += c2 * __uint_as_float(r1.y);
        sum += c3 * __uint_as_float(r1.w);
    }
    for (; c >= 2; c -= 2, s += 2) {
        uint4v r = __builtin_nontemporal_load(reinterpret_cast<const uint4v*>(rec2 + s));
        sum += cur[r.x] * __uint_as_float(r.y);
        sum += cur[r.z] * __uint_as_float(r.w);
    }
    if (c) {
        uint2 r = rec2[s];
        sum += cur[r.x] * __uint_as_float(r.y);
    }
    nxt[n] = sum;
}

// ---------------- fallback path (device atomics, small workspace) ----------------

__global__ void zero_kernel(float* __restrict__ p, int n) {
    int i = blockIdx.x * blockDim.x + threadIdx.x;
    int stride = gridDim.x * blockDim.x;
    for (; i < n; i += stride) p[i] = 0.0f;
}

__global__ __launch_bounds__(256) void hop_atomic(
    const int* __restrict__ src, const int* __restrict__ dst,
    const float* __restrict__ ew, const float* __restrict__ cur,
    float* __restrict__ nxt) {
    int e = blockIdx.x * blockDim.x + threadIdx.x;
    if (e * 4 < NEDGE) {
        int4   s = ((const int4*)src)[e];
        int4   d = ((const int4*)dst)[e];
        float4 w = ((const float4*)ew)[e];
        atomicAdd(&nxt[d.x], cur[s.x] * w.x);
        atomicAdd(&nxt[d.y], cur[s.y] * w.y);
        atomicAdd(&nxt[d.z], cur[s.z] * w.z);
        atomicAdd(&nxt[d.w], cur[s.w] * w.w);
    }
}

// ---------------- finalize: 5->64 matvec + BatchNorm over features ----------------

__global__ __launch_bounds__(256) void finalize_kernel(
    const float* __restrict__ x,  const float* __restrict__ f1,
    const float* __restrict__ f2, const float* __restrict__ f3,
    const float* __restrict__ f4, const float* __restrict__ W,
    const float* __restrict__ bias, const float* __restrict__ gamma,
    const float* __restrict__ beta, float* __restrict__ out) {
    int lane = threadIdx.x & 63;
    int waveInBlock = threadIdx.x >> 6;
    int wavesPerBlock = blockDim.x >> 6;
    int gwave  = blockIdx.x * wavesPerBlock + waveInBlock;
    int nwaves = gridDim.x * wavesPerBlock;

    float w0 = W[lane * 5 + 0];
    float w1 = W[lane * 5 + 1];
    float w2 = W[lane * 5 + 2];
    float w3 = W[lane * 5 + 3];
    float w4 = W[lane * 5 + 4];
    float b  = bias[lane];

    for (int n = gwave; n < N_USERS; n += nwaves) {
        float c0 = x[n], c1 = f1[n], c2 = f2[n], c3 = f3[n], c4 = f4[n];
        float y = b + c0 * w0 + c1 * w1 + c2 * w2 + c3 * w3 + c4 * w4;

        float s = y;
        #pragma unroll
        for (int off = 32; off; off >>= 1) s += __shfl_xor(s, off);
        float mean = s * (1.0f / 64.0f);

        float d = y - mean;
        float v = d * d;
        #pragma unroll
        for (int off = 32; off; off >>= 1) v += __shfl_xor(v, off);
        float var = v * (1.0f / 64.0f);

        float o = d * rsqrtf(var + BN_EPS) * gamma[n] + beta[n];
        __builtin_nontemporal_store(o, &out[(size_t)n * OUT_F + lane]);
    }
}

extern "C" void kernel_launch(void* const* d_in, const int* in_sizes, int n_in,
                              void* d_out, int out_size, void* d_ws, size_t ws_size,
                              hipStream_t stream) {
    const float* x     = (const float*)d_in[0];
    const int*   ei    = (const int*)d_in[1];
    const float* ew    = (const float*)d_in[2];
    const float* W     = (const float*)d_in[3];
    const float* bias  = (const float*)d_in[4];
    const float* gamma = (const float*)d_in[5];
    const float* beta  = (const float*)d_in[6];
    float* out = (float*)d_out;

    const int* src = ei;
    const int* dst = ei + NEDGE;

    // Workspace layout (total ~289.4MB; known-available >= 304MB)
    float* f = (float*)d_ws;                                   // 16MB
    uint2* rec = (uint2*)(f + 4ull * N_USERS);                 // 268.3MB
    unsigned* cursors = (unsigned*)(rec + (size_t)NB * CAP);   // 4KB (padded)
    unsigned* rowstart = cursors + 1024;                       // 4.01MB
    unsigned char* rowcnt = (unsigned char*)(rowstart + (size_t)NB * S_BUCKET);  // 1MB
    size_t needed = 16000000ull + (size_t)NB * CAP * 8 + 4096
                  + (size_t)NB * S_BUCKET * 4 + (size_t)NB * S_BUCKET;

    // Sorted record array lives in d_out (dead until finalize): 268.3MB <= 268.4MB
    uint2* rec2 = (uint2*)d_out;

    if (ws_size >= needed && (size_t)out_size >= (size_t)NB * CAP * 8) {
        init_cursors<<<1, 256, 0, stream>>>(cursors);
        scatter_bin<<<SCAT_BLOCKS, 256, 0, stream>>>(src, dst, ew, rec, cursors);
        sort_bucket<<<SORT_BLOCKS, 256, 0, stream>>>(rec, cursors, rec2, rowstart, rowcnt);
        const float* cur = x;
        for (int h = 0; h < 4; ++h) {
            float* nxt = f + (size_t)h * N_USERS;
            hop_csr<<<(N_USERS + 255) / 256, 256, 0, stream>>>(rec2, rowstart, rowcnt, cur, nxt);
            cur = nxt;
        }
    } else {
        zero_kernel<<<4096, 256, 0, stream>>>(f, 4 * N_USERS);
        const float* cur = x;
        for (int h = 0; h < 4; ++h) {
            float* nxt = f + (size_t)h * N_USERS;
            hop_atomic<<<NEDGE / 4 / 256, 256, 0, stream>>>(src, dst, ew, cur, nxt);
            cur = nxt;
        }
    }

    finalize_kernel<<<2048, 256, 0, stream>>>(
        x, f, f + N_USERS, f + 2 * N_USERS, f + 3 * N_USERS,
        W, bias, gamma, beta, out);
}

// Round 5
// 6671.362 us; speedup vs baseline: 1.0003x; 1.0003x over previous
//
#include <hip/hip_runtime.h>

#define N_USERS 1000000
#define NEDGE   32000000
#define OUT_F   64
#define BN_EPS  1e-5f

// Destination binning geometry.
// S_BUCKET=4096 is the max where meta packs: dst_local(12b)<<20 | src(20b).
#define SBITS     12
#define S_BUCKET  4096                     // nodes per bucket
#define NB        245                      // ceil(N_USERS / S_BUCKET)
// CAP: mean 130612, sigma ~361; slack ~17 sigma. Padded rec (NB*CAP*8=268.3MB)
// lives in workspace. The SORTED array rec2 is COMPACT (exactly NEDGE*8 =
// 256,000,000 B) and lives in d_out (exactly 256,000,000 B). Round-4 bug:
// padded rec2 (268.3MB) did not fit d_out -> fallback path ran.
#define CAP       136896
#define SCAT_BLOCKS 1024
#define CHUNK     (NEDGE / SCAT_BLOCKS)    // 31250
#define SORT_BLOCKS 64                     // bounds sort's scattered-write set (~8MB/XCD)

typedef unsigned int uint4v __attribute__((ext_vector_type(4)));  // nontemporal-loadable

// ---------------- binned path ----------------

__global__ void init_cursors(unsigned* __restrict__ cursors) {
    int i = blockIdx.x * blockDim.x + threadIdx.x;
    if (i < NB) cursors[i] = (unsigned)i * CAP;
}

// Partition edges by destination bucket. Per block: LDS histogram of its chunk,
// one global atomicAdd per non-empty bucket to reserve a contiguous range, then
// scatter packed 8B records (meta = dst_local<<20 | src, weight bits).
__global__ __launch_bounds__(256) void scatter_bin(
    const int* __restrict__ src, const int* __restrict__ dst,
    const float* __restrict__ ew, uint2* __restrict__ rec,
    unsigned* __restrict__ cursors) {
    __shared__ unsigned cnt[NB];
    __shared__ unsigned base[NB];
    int tid = threadIdx.x;
    int start = blockIdx.x * CHUNK;
    int end = start + CHUNK;

    for (int i = tid; i < NB; i += 256) cnt[i] = 0;
    __syncthreads();
    for (int i = start + tid; i < end; i += 256) {
        int d = __builtin_nontemporal_load(&dst[i]);
        atomicAdd(&cnt[d >> SBITS], 1u);
    }
    __syncthreads();
    for (int i = tid; i < NB; i += 256) {
        unsigned c = cnt[i];
        base[i] = c ? atomicAdd(&cursors[i], c) : 0u;
    }
    __syncthreads();
    for (int i = tid; i < NB; i += 256) cnt[i] = 0;
    __syncthreads();
    for (int i = start + tid; i < end; i += 256) {
        int d = __builtin_nontemporal_load(&dst[i]);
        int s = __builtin_nontemporal_load(&src[i]);
        float w = __builtin_nontemporal_load(&ew[i]);
        int b = d >> SBITS;
        unsigned p = base[b] + atomicAdd(&cnt[b], 1u);
        unsigned meta = ((unsigned)(d & (S_BUCKET - 1)) << 20) | (unsigned)s;
        rec[p] = make_uint2(meta, __float_as_uint(w));
    }
}

// Exclusive prefix over per-bucket counts -> compact output base per bucket.
__global__ __launch_bounds__(256) void compute_bases(
    const unsigned* __restrict__ cursors, unsigned* __restrict__ bases) {
    __shared__ unsigned c[256];
    int t = threadIdx.x;
    c[t] = (t < NB) ? (cursors[t] - (unsigned)t * CAP) : 0u;
    __syncthreads();
    if (t == 0) {
        unsigned run = 0;
        for (int b = 0; b < NB; ++b) { unsigned v = c[b]; c[b] = run; run += v; }
    }
    __syncthreads();
    if (t < NB) bases[t] = c[t];
}

// Counting-sort each bucket's records by exact dst_local (4096 keys), writing
// (src, weight) records grouped by destination COMPACTLY into rec2 (in d_out),
// and emitting per-node rowstart (index into rec2) + rowcnt. Done ONCE; the
// 4 hop passes then need no atomics at all.
__global__ __launch_bounds__(256) void sort_bucket(
    const uint2* __restrict__ rec, const unsigned* __restrict__ cursors,
    const unsigned* __restrict__ bases, uint2* __restrict__ rec2,
    unsigned* __restrict__ rowstart, unsigned char* __restrict__ rowcnt) {
    __shared__ unsigned offs[S_BUCKET];   // histogram -> exclusive offsets
    __shared__ unsigned cnt2[S_BUCKET];
    __shared__ unsigned chunkT[256];
    int tid = threadIdx.x;

    for (int b = blockIdx.x; b < NB; b += SORT_BLOCKS) {
        for (int k = tid; k < S_BUCKET; k += 256) { offs[k] = 0; cnt2[k] = 0; }
        __syncthreads();

        unsigned start = (unsigned)b * CAP;          // even -> 16B-aligned
        unsigned n = cursors[b] - start;
        unsigned gbase = bases[b];                   // compact output base
        const uint2* bp = rec + start;

        // pass A: histogram of dst_local
        unsigned i = 2u * (unsigned)tid;
        for (; i + 2u <= n; i += 512u) {
            uint4v r = __builtin_nontemporal_load(reinterpret_cast<const uint4v*>(bp + i));
            atomicAdd(&offs[r.x >> 20], 1u);
            atomicAdd(&offs[r.z >> 20], 1u);
        }
        if (i < n) {                                  // odd tail (exactly one thread)
            uint2 r = bp[i];
            atomicAdd(&offs[r.x >> 20], 1u);
        }
        __syncthreads();

        // per-node counts (before in-place scan destroys them)
        int nb0 = b << SBITS;
        for (int k = tid; k < S_BUCKET; k += 256)
            rowcnt[nb0 + k] = (unsigned char)offs[k];   // Poisson(32): >255 impossible
        __syncthreads();

        // exclusive prefix sum over offs[4096]: 16 cells/thread + serial chunk scan
        {
            int base = tid * 16;
            unsigned run = 0;
            for (int k = 0; k < 16; ++k) { unsigned v = offs[base + k]; offs[base + k] = run; run += v; }
            chunkT[tid] = run;
        }
        __syncthreads();
        if (tid == 0) {
            unsigned run = 0;
            for (int t = 0; t < 256; ++t) { unsigned v = chunkT[t]; chunkT[t] = run; run += v; }
        }
        __syncthreads();
        {
            int base = tid * 16;
            unsigned add = chunkT[tid];
            for (int k = 0; k < 16; ++k) offs[base + k] += add;
        }
        __syncthreads();

        for (int k = tid; k < S_BUCKET; k += 256)
            rowstart[nb0 + k] = gbase + offs[k];

        // pass B: scatter records to exact sorted positions (src, weight)
        i = 2u * (unsigned)tid;
        for (; i + 2u <= n; i += 512u) {
            uint4v r = __builtin_nontemporal_load(reinterpret_cast<const uint4v*>(bp + i));
            unsigned d0 = r.x >> 20, d1 = r.z >> 20;
            unsigned p0 = offs[d0] + atomicAdd(&cnt2[d0], 1u);
            unsigned p1 = offs[d1] + atomicAdd(&cnt2[d1], 1u);
            rec2[gbase + p0] = make_uint2(r.x & 0xFFFFFu, r.y);
            rec2[gbase + p1] = make_uint2(r.z & 0xFFFFFu, r.w);
        }
        if (i < n) {
            uint2 r = bp[i];
            unsigned d0 = r.x >> 20;
            unsigned p0 = offs[d0] + atomicAdd(&cnt2[d0], 1u);
            rec2[gbase + p0] = make_uint2(r.x & 0xFFFFFu, r.y);
        }
        __syncthreads();   // before next bucket re-zeroes offs/cnt2
    }
}

// CSR hop: one thread per destination node, register accumulation, no atomics.
// Records are contiguous per node; read 4/iter (two 16B nt loads) for MLP.
__global__ __launch_bounds__(256) void hop_csr(
    const uint2* __restrict__ rec2, const unsigned* __restrict__ rowstart,
    const unsigned char* __restrict__ rowcnt, const float* __restrict__ cur,
    float* __restrict__ nxt) {
    int n = blockIdx.x * 256 + threadIdx.x;
    if (n >= N_USERS) return;
    unsigned s = rowstart[n];
    int c = rowcnt[n];
    float sum = 0.0f;
    if ((s & 1u) && c > 0) {                       // align to 16B
        uint2 r = rec2[s];
        sum += cur[r.x] * __uint_as_float(r.y);
        ++s; --c;
    }
    for (; c >= 4; c -= 4, s += 4) {
        uint4v r0 = __builtin_nontemporal_load(reinterpret_cast<const uint4v*>(rec2 + s));
        uint4v r1 = __builtin_nontemporal_load(reinterpret_cast<const uint4v*>(rec2 + s + 2));
        float c0 = cur[r0.x], c1 = cur[r0.z], c2 = cur[r1.x], c3 = cur[r1.z];
        sum += c0 * __uint_as_float(r0.y);
        sum += c1 * __uint_as_float(r0.w);
        sum += c2 * __uint_as_float(r1.y);
        sum += c3 * __uint_as_float(r1.w);
    }
    for (; c >= 2; c -= 2, s += 2) {
        uint4v r = __builtin_nontemporal_load(reinterpret_cast<const uint4v*>(rec2 + s));
        sum += cur[r.x] * __uint_as_float(r.y);
        sum += cur[r.z] * __uint_as_float(r.w);
    }
    if (c) {
        uint2 r = rec2[s];
        sum += cur[r.x] * __uint_as_float(r.y);
    }
    nxt[n] = sum;
}

// ---------------- fallback path (device atomics, small workspace) ----------------

__global__ void zero_kernel(float* __restrict__ p, int n) {
    int i = blockIdx.x * blockDim.x + threadIdx.x;
    int stride = gridDim.x * blockDim.x;
    for (; i < n; i += stride) p[i] = 0.0f;
}

__global__ __launch_bounds__(256) void hop_atomic(
    const int* __restrict__ src, const int* __restrict__ dst,
    const float* __restrict__ ew, const float* __restrict__ cur,
    float* __restrict__ nxt) {
    int e = blockIdx.x * blockDim.x + threadIdx.x;
    if (e * 4 < NEDGE) {
        int4   s = ((const int4*)src)[e];
        int4   d = ((const int4*)dst)[e];
        float4 w = ((const float4*)ew)[e];
        atomicAdd(&nxt[d.x], cur[s.x] * w.x);
        atomicAdd(&nxt[d.y], cur[s.y] * w.y);
        atomicAdd(&nxt[d.z], cur[s.z] * w.z);
        atomicAdd(&nxt[d.w], cur[s.w] * w.w);
    }
}

// ---------------- finalize: 5->64 matvec + BatchNorm over features ----------------

__global__ __launch_bounds__(256) void finalize_kernel(
    const float* __restrict__ x,  const float* __restrict__ f1,
    const float* __restrict__ f2, const float* __restrict__ f3,
    const float* __restrict__ f4, const float* __restrict__ W,
    const float* __restrict__ bias, const float* __restrict__ gamma,
    const float* __restrict__ beta, float* __restrict__ out) {
    int lane = threadIdx.x & 63;
    int waveInBlock = threadIdx.x >> 6;
    int wavesPerBlock = blockDim.x >> 6;
    int gwave  = blockIdx.x * wavesPerBlock + waveInBlock;
    int nwaves = gridDim.x * wavesPerBlock;

    float w0 = W[lane * 5 + 0];
    float w1 = W[lane * 5 + 1];
    float w2 = W[lane * 5 + 2];
    float w3 = W[lane * 5 + 3];
    float w4 = W[lane * 5 + 4];
    float b  = bias[lane];

    for (int n = gwave; n < N_USERS; n += nwaves) {
        float c0 = x[n], c1 = f1[n], c2 = f2[n], c3 = f3[n], c4 = f4[n];
        float y = b + c0 * w0 + c1 * w1 + c2 * w2 + c3 * w3 + c4 * w4;

        float s = y;
        #pragma unroll
        for (int off = 32; off; off >>= 1) s += __shfl_xor(s, off);
        float mean = s * (1.0f / 64.0f);

        float d = y - mean;
        float v = d * d;
        #pragma unroll
        for (int off = 32; off; off >>= 1) v += __shfl_xor(v, off);
        float var = v * (1.0f / 64.0f);

        float o = d * rsqrtf(var + BN_EPS) * gamma[n] + beta[n];
        __builtin_nontemporal_store(o, &out[(size_t)n * OUT_F + lane]);
    }
}

extern "C" void kernel_launch(void* const* d_in, const int* in_sizes, int n_in,
                              void* d_out, int out_size, void* d_ws, size_t ws_size,
                              hipStream_t stream) {
    const float* x     = (const float*)d_in[0];
    const int*   ei    = (const int*)d_in[1];
    const float* ew    = (const float*)d_in[2];
    const float* W     = (const float*)d_in[3];
    const float* bias  = (const float*)d_in[4];
    const float* gamma = (const float*)d_in[5];
    const float* beta  = (const float*)d_in[6];
    float* out = (float*)d_out;

    const int* src = ei;
    const int* dst = ei + NEDGE;

    // Workspace layout (total ~289.4MB; known-available >= 304MB)
    float* f = (float*)d_ws;                                   // 16MB
    uint2* rec = (uint2*)(f + 4ull * N_USERS);                 // 268.3MB (padded)
    unsigned* cursors = (unsigned*)(rec + (size_t)NB * CAP);   // 4KB (padded)
    unsigned* bases = cursors + 1024;                          // 4KB (padded)
    unsigned* rowstart = bases + 1024;                         // 4.01MB
    unsigned char* rowcnt = (unsigned char*)(rowstart + (size_t)NB * S_BUCKET);  // 1MB
    size_t needed = 16000000ull + (size_t)NB * CAP * 8 + 8192
                  + (size_t)NB * S_BUCKET * 4 + (size_t)NB * S_BUCKET;

    // Compact sorted record array lives in d_out (dead until finalize):
    // NEDGE*8 = 256,000,000 B == out_size exactly.
    uint2* rec2 = (uint2*)d_out;

    if (ws_size >= needed && (size_t)out_size >= (size_t)NEDGE * 8) {
        init_cursors<<<1, 256, 0, stream>>>(cursors);
        scatter_bin<<<SCAT_BLOCKS, 256, 0, stream>>>(src, dst, ew, rec, cursors);
        compute_bases<<<1, 256, 0, stream>>>(cursors, bases);
        sort_bucket<<<SORT_BLOCKS, 256, 0, stream>>>(rec, cursors, bases, rec2, rowstart, rowcnt);
        const float* cur = x;
        for (int h = 0; h < 4; ++h) {
            float* nxt = f + (size_t)h * N_USERS;
            hop_csr<<<(N_USERS + 255) / 256, 256, 0, stream>>>(rec2, rowstart, rowcnt, cur, nxt);
            cur = nxt;
        }
    } else {
        zero_kernel<<<4096, 256, 0, stream>>>(f, 4 * N_USERS);
        const float* cur = x;
        for (int h = 0; h < 4; ++h) {
            float* nxt = f + (size_t)h * N_USERS;
            hop_atomic<<<NEDGE / 4 / 256, 256, 0, stream>>>(src, dst, ew, cur, nxt);
            cur = nxt;
        }
    }

    finalize_kernel<<<2048, 256, 0, stream>>>(
        x, f, f + N_USERS, f + 2 * N_USERS, f + 3 * N_USERS,
        W, bias, gamma, beta, out);
}

// Round 6
// 4127.777 us; speedup vs baseline: 1.6168x; 1.6162x over previous
//
#include <hip/hip_runtime.h>

#define N_USERS 1000000
#define NEDGE   32000000
#define OUT_F   64
#define BN_EPS  1e-5f

// Destination binning geometry.
// S_BUCKET=4096 is the max where meta packs: dst_local(12b)<<20 | src(20b).
#define SBITS     12
#define S_BUCKET  4096                     // nodes per bucket
#define NB        245                      // ceil(N_USERS / S_BUCKET)
// CAP: mean 130612, sigma ~361; slack ~17 sigma. Padded rec (NB*CAP*8=268.3MB)
// lives in workspace. The SORTED array rec2 is COMPACT (exactly NEDGE*8 =
// 256,000,000 B) and lives in d_out (N_USERS*OUT_F*4 = 256,000,000 B).
// Rounds 4-5 bug: gated this on the runtime out_size parameter, whose UNITS
// are not bytes (guard failed, silently ran the 6.7ms fallback). The capacity
// fact is compile-time provable, so assert it statically instead.
#define CAP       136896
#define SCAT_BLOCKS 1024
#define CHUNK     (NEDGE / SCAT_BLOCKS)    // 31250
#define SORT_BLOCKS 64                     // bounds sort's scattered-write set

static_assert((unsigned long long)NEDGE * 8ull <=
              (unsigned long long)N_USERS * OUT_F * 4ull,
              "compact rec2 must fit in d_out");

typedef unsigned int uint4v __attribute__((ext_vector_type(4)));  // nontemporal-loadable

// ---------------- binned path ----------------

__global__ void init_cursors(unsigned* __restrict__ cursors) {
    int i = blockIdx.x * blockDim.x + threadIdx.x;
    if (i < NB) cursors[i] = (unsigned)i * CAP;
}

// Partition edges by destination bucket. Per block: LDS histogram of its chunk,
// one global atomicAdd per non-empty bucket to reserve a contiguous range, then
// scatter packed 8B records (meta = dst_local<<20 | src, weight bits).
__global__ __launch_bounds__(256) void scatter_bin(
    const int* __restrict__ src, const int* __restrict__ dst,
    const float* __restrict__ ew, uint2* __restrict__ rec,
    unsigned* __restrict__ cursors) {
    __shared__ unsigned cnt[NB];
    __shared__ unsigned base[NB];
    int tid = threadIdx.x;
    int start = blockIdx.x * CHUNK;
    int end = start + CHUNK;

    for (int i = tid; i < NB; i += 256) cnt[i] = 0;
    __syncthreads();
    for (int i = start + tid; i < end; i += 256) {
        int d = __builtin_nontemporal_load(&dst[i]);
        atomicAdd(&cnt[d >> SBITS], 1u);
    }
    __syncthreads();
    for (int i = tid; i < NB; i += 256) {
        unsigned c = cnt[i];
        base[i] = c ? atomicAdd(&cursors[i], c) : 0u;
    }
    __syncthreads();
    for (int i = tid; i < NB; i += 256) cnt[i] = 0;
    __syncthreads();
    for (int i = start + tid; i < end; i += 256) {
        int d = __builtin_nontemporal_load(&dst[i]);
        int s = __builtin_nontemporal_load(&src[i]);
        float w = __builtin_nontemporal_load(&ew[i]);
        int b = d >> SBITS;
        unsigned p = base[b] + atomicAdd(&cnt[b], 1u);
        unsigned meta = ((unsigned)(d & (S_BUCKET - 1)) << 20) | (unsigned)s;
        rec[p] = make_uint2(meta, __float_as_uint(w));
    }
}

// Exclusive prefix over per-bucket counts -> compact output base per bucket.
__global__ __launch_bounds__(256) void compute_bases(
    const unsigned* __restrict__ cursors, unsigned* __restrict__ bases) {
    __shared__ unsigned c[256];
    int t = threadIdx.x;
    c[t] = (t < NB) ? (cursors[t] - (unsigned)t * CAP) : 0u;
    __syncthreads();
    if (t == 0) {
        unsigned run = 0;
        for (int b = 0; b < NB; ++b) { unsigned v = c[b]; c[b] = run; run += v; }
    }
    __syncthreads();
    if (t < NB) bases[t] = c[t];
}

// Counting-sort each bucket's records by exact dst_local (4096 keys), writing
// (src, weight) records grouped by destination COMPACTLY into rec2 (in d_out),
// and emitting per-node rowstart (index into rec2) + rowcnt. Done ONCE; the
// 4 hop passes then need no atomics at all.
__global__ __launch_bounds__(256) void sort_bucket(
    const uint2* __restrict__ rec, const unsigned* __restrict__ cursors,
    const unsigned* __restrict__ bases, uint2* __restrict__ rec2,
    unsigned* __restrict__ rowstart, unsigned char* __restrict__ rowcnt) {
    __shared__ unsigned offs[S_BUCKET];   // histogram -> exclusive offsets
    __shared__ unsigned cnt2[S_BUCKET];
    __shared__ unsigned chunkT[256];
    int tid = threadIdx.x;

    for (int b = blockIdx.x; b < NB; b += SORT_BLOCKS) {
        for (int k = tid; k < S_BUCKET; k += 256) { offs[k] = 0; cnt2[k] = 0; }
        __syncthreads();

        unsigned start = (unsigned)b * CAP;          // even -> 16B-aligned
        unsigned n = cursors[b] - start;
        unsigned gbase = bases[b];                   // compact output base
        const uint2* bp = rec + start;

        // pass A: histogram of dst_local
        unsigned i = 2u * (unsigned)tid;
        for (; i + 2u <= n; i += 512u) {
            uint4v r = __builtin_nontemporal_load(reinterpret_cast<const uint4v*>(bp + i));
            atomicAdd(&offs[r.x >> 20], 1u);
            atomicAdd(&offs[r.z >> 20], 1u);
        }
        if (i < n) {                                  // odd tail (exactly one thread)
            uint2 r = bp[i];
            atomicAdd(&offs[r.x >> 20], 1u);
        }
        __syncthreads();

        // per-node counts (before in-place scan destroys them)
        int nb0 = b << SBITS;
        for (int k = tid; k < S_BUCKET; k += 256)
            rowcnt[nb0 + k] = (unsigned char)offs[k];   // Poisson(32): >255 impossible
        __syncthreads();

        // exclusive prefix sum over offs[4096]: 16 cells/thread + serial chunk scan
        {
            int base = tid * 16;
            unsigned run = 0;
            for (int k = 0; k < 16; ++k) { unsigned v = offs[base + k]; offs[base + k] = run; run += v; }
            chunkT[tid] = run;
        }
        __syncthreads();
        if (tid == 0) {
            unsigned run = 0;
            for (int t = 0; t < 256; ++t) { unsigned v = chunkT[t]; chunkT[t] = run; run += v; }
        }
        __syncthreads();
        {
            int base = tid * 16;
            unsigned add = chunkT[tid];
            for (int k = 0; k < 16; ++k) offs[base + k] += add;
        }
        __syncthreads();

        for (int k = tid; k < S_BUCKET; k += 256)
            rowstart[nb0 + k] = gbase + offs[k];

        // pass B: scatter records to exact sorted positions (src, weight)
        i = 2u * (unsigned)tid;
        for (; i + 2u <= n; i += 512u) {
            uint4v r = __builtin_nontemporal_load(reinterpret_cast<const uint4v*>(bp + i));
            unsigned d0 = r.x >> 20, d1 = r.z >> 20;
            unsigned p0 = offs[d0] + atomicAdd(&cnt2[d0], 1u);
            unsigned p1 = offs[d1] + atomicAdd(&cnt2[d1], 1u);
            rec2[gbase + p0] = make_uint2(r.x & 0xFFFFFu, r.y);
            rec2[gbase + p1] = make_uint2(r.z & 0xFFFFFu, r.w);
        }
        if (i < n) {
            uint2 r = bp[i];
            unsigned d0 = r.x >> 20;
            unsigned p0 = offs[d0] + atomicAdd(&cnt2[d0], 1u);
            rec2[gbase + p0] = make_uint2(r.x & 0xFFFFFu, r.y);
        }
        __syncthreads();   // before next bucket re-zeroes offs/cnt2
    }
}

// CSR hop: one thread per destination node, register accumulation, no atomics.
// Records are contiguous per node; read 4/iter (two 16B nt loads) for MLP.
__global__ __launch_bounds__(256) void hop_csr(
    const uint2* __restrict__ rec2, const unsigned* __restrict__ rowstart,
    const unsigned char* __restrict__ rowcnt, const float* __restrict__ cur,
    float* __restrict__ nxt) {
    int n = blockIdx.x * 256 + threadIdx.x;
    if (n >= N_USERS) return;
    unsigned s = rowstart[n];
    int c = rowcnt[n];
    float sum = 0.0f;
    if ((s & 1u) && c > 0) {                       // align to 16B
        uint2 r = rec2[s];
        sum += cur[r.x] * __uint_as_float(r.y);
        ++s; --c;
    }
    for (; c >= 4; c -= 4, s += 4) {
        uint4v r0 = __builtin_nontemporal_load(reinterpret_cast<const uint4v*>(rec2 + s));
        uint4v r1 = __builtin_nontemporal_load(reinterpret_cast<const uint4v*>(rec2 + s + 2));
        float c0 = cur[r0.x], c1 = cur[r0.z], c2 = cur[r1.x], c3 = cur[r1.z];
        sum += c0 * __uint_as_float(r0.y);
        sum += c1 * __uint_as_float(r0.w);
        sum += c2 * __uint_as_float(r1.y);
        sum += c3 * __uint_as_float(r1.w);
    }
    for (; c >= 2; c -= 2, s += 2) {
        uint4v r = __builtin_nontemporal_load(reinterpret_cast<const uint4v*>(rec2 + s));
        sum += cur[r.x] * __uint_as_float(r.y);
        sum += cur[r.z] * __uint_as_float(r.w);
    }
    if (c) {
        uint2 r = rec2[s];
        sum += cur[r.x] * __uint_as_float(r.y);
    }
    nxt[n] = sum;
}

// ---------------- fallback path (device atomics, small workspace) ----------------

__global__ void zero_kernel(float* __restrict__ p, int n) {
    int i = blockIdx.x * blockDim.x + threadIdx.x;
    int stride = gridDim.x * blockDim.x;
    for (; i < n; i += stride) p[i] = 0.0f;
}

__global__ __launch_bounds__(256) void hop_atomic(
    const int* __restrict__ src, const int* __restrict__ dst,
    const float* __restrict__ ew, const float* __restrict__ cur,
    float* __restrict__ nxt) {
    int e = blockIdx.x * blockDim.x + threadIdx.x;
    if (e * 4 < NEDGE) {
        int4   s = ((const int4*)src)[e];
        int4   d = ((const int4*)dst)[e];
        float4 w = ((const float4*)ew)[e];
        atomicAdd(&nxt[d.x], cur[s.x] * w.x);
        atomicAdd(&nxt[d.y], cur[s.y] * w.y);
        atomicAdd(&nxt[d.z], cur[s.z] * w.z);
        atomicAdd(&nxt[d.w], cur[s.w] * w.w);
    }
}

// ---------------- finalize: 5->64 matvec + BatchNorm over features ----------------

__global__ __launch_bounds__(256) void finalize_kernel(
    const float* __restrict__ x,  const float* __restrict__ f1,
    const float* __restrict__ f2, const float* __restrict__ f3,
    const float* __restrict__ f4, const float* __restrict__ W,
    const float* __restrict__ bias, const float* __restrict__ gamma,
    const float* __restrict__ beta, float* __restrict__ out) {
    int lane = threadIdx.x & 63;
    int waveInBlock = threadIdx.x >> 6;
    int wavesPerBlock = blockDim.x >> 6;
    int gwave  = blockIdx.x * wavesPerBlock + waveInBlock;
    int nwaves = gridDim.x * wavesPerBlock;

    float w0 = W[lane * 5 + 0];
    float w1 = W[lane * 5 + 1];
    float w2 = W[lane * 5 + 2];
    float w3 = W[lane * 5 + 3];
    float w4 = W[lane * 5 + 4];
    float b  = bias[lane];

    for (int n = gwave; n < N_USERS; n += nwaves) {
        float c0 = x[n], c1 = f1[n], c2 = f2[n], c3 = f3[n], c4 = f4[n];
        float y = b + c0 * w0 + c1 * w1 + c2 * w2 + c3 * w3 + c4 * w4;

        float s = y;
        #pragma unroll
        for (int off = 32; off; off >>= 1) s += __shfl_xor(s, off);
        float mean = s * (1.0f / 64.0f);

        float d = y - mean;
        float v = d * d;
        #pragma unroll
        for (int off = 32; off; off >>= 1) v += __shfl_xor(v, off);
        float var = v * (1.0f / 64.0f);

        float o = d * rsqrtf(var + BN_EPS) * gamma[n] + beta[n];
        __builtin_nontemporal_store(o, &out[(size_t)n * OUT_F + lane]);
    }
}

extern "C" void kernel_launch(void* const* d_in, const int* in_sizes, int n_in,
                              void* d_out, int out_size, void* d_ws, size_t ws_size,
                              hipStream_t stream) {
    const float* x     = (const float*)d_in[0];
    const int*   ei    = (const int*)d_in[1];
    const float* ew    = (const float*)d_in[2];
    const float* W     = (const float*)d_in[3];
    const float* bias  = (const float*)d_in[4];
    const float* gamma = (const float*)d_in[5];
    const float* beta  = (const float*)d_in[6];
    float* out = (float*)d_out;

    const int* src = ei;
    const int* dst = ei + NEDGE;

    // Workspace layout (total ~289.4MB; known-available >= 304MB from rounds 0-1)
    float* f = (float*)d_ws;                                   // 16MB
    uint2* rec = (uint2*)(f + 4ull * N_USERS);                 // 268.3MB (padded)
    unsigned* cursors = (unsigned*)(rec + (size_t)NB * CAP);   // 4KB (padded)
    unsigned* bases = cursors + 1024;                          // 4KB (padded)
    unsigned* rowstart = bases + 1024;                         // 4.01MB
    unsigned char* rowcnt = (unsigned char*)(rowstart + (size_t)NB * S_BUCKET);  // 1MB
    size_t needed = 16000000ull + (size_t)NB * CAP * 8 + 8192
                  + (size_t)NB * S_BUCKET * 4 + (size_t)NB * S_BUCKET;

    // Compact sorted record array lives in d_out (dead until finalize).
    // Capacity proven by static_assert; do NOT trust out_size's units.
    uint2* rec2 = (uint2*)d_out;

    if (ws_size >= needed) {
        init_cursors<<<1, 256, 0, stream>>>(cursors);
        scatter_bin<<<SCAT_BLOCKS, 256, 0, stream>>>(src, dst, ew, rec, cursors);
        compute_bases<<<1, 256, 0, stream>>>(cursors, bases);
        sort_bucket<<<SORT_BLOCKS, 256, 0, stream>>>(rec, cursors, bases, rec2, rowstart, rowcnt);
        const float* cur = x;
        for (int h = 0; h < 4; ++h) {
            float* nxt = f + (size_t)h * N_USERS;
            hop_csr<<<(N_USERS + 255) / 256, 256, 0, stream>>>(rec2, rowstart, rowcnt, cur, nxt);
            cur = nxt;
        }
    } else {
        zero_kernel<<<4096, 256, 0, stream>>>(f, 4 * N_USERS);
        const float* cur = x;
        for (int h = 0; h < 4; ++h) {
            float* nxt = f + (size_t)h * N_USERS;
            hop_atomic<<<NEDGE / 4 / 256, 256, 0, stream>>>(src, dst, ew, cur, nxt);
            cur = nxt;
        }
    }

    finalize_kernel<<<2048, 256, 0, stream>>>(
        x, f, f + N_USERS, f + 2 * N_USERS, f + 3 * N_USERS,
        W, bias, gamma, beta, out);
}

// Round 7
// 2614.987 us; speedup vs baseline: 2.5521x; 1.5785x over previous
//
#include <hip/hip_runtime.h>

#define N_USERS 1000000
#define NEDGE   32000000
#define OUT_F   64
#define BN_EPS  1e-5f

// Destination binning geometry.
// S_BUCKET=4096 is the max where meta packs: dst_local(12b)<<20 | src(20b).
#define SBITS     12
#define S_BUCKET  4096                     // nodes per bucket
#define NB        245                      // ceil(N_USERS / S_BUCKET)
// CAP: mean 130612, sigma ~361; slack ~17 sigma. Padded rec (NB*CAP*8=268.3MB)
// lives in workspace. The SORTED array rec2 is COMPACT (exactly NEDGE*8 =
// 256,000,000 B) and lives in d_out (N_USERS*OUT_F*4 = 256,000,000 B).
// Do NOT gate on the runtime out_size param: its units are not bytes
// (rounds 4-5 silently ran the 6.7ms fallback because of that guard).
#define CAP       136896
#define SCAT_BLOCKS 1024
#define CHUNK     (NEDGE / SCAT_BLOCKS)    // 31250

#define HOP_NODES 256                      // nodes per hop block
#define HOP_CH    2048                     // records staged per LDS chunk (16KB)

static_assert((unsigned long long)NEDGE * 8ull <=
              (unsigned long long)N_USERS * OUT_F * 4ull,
              "compact rec2 must fit in d_out");

typedef unsigned int uint4v __attribute__((ext_vector_type(4)));  // nontemporal-loadable

// ---------------- binned path ----------------

__global__ void init_cursors(unsigned* __restrict__ cursors) {
    int i = blockIdx.x * blockDim.x + threadIdx.x;
    if (i < NB) cursors[i] = (unsigned)i * CAP;
}

// Partition edges by destination bucket. Per block: LDS histogram of its chunk,
// one global atomicAdd per non-empty bucket to reserve a contiguous range, then
// scatter packed 8B records (meta = dst_local<<20 | src, weight bits).
__global__ __launch_bounds__(256) void scatter_bin(
    const int* __restrict__ src, const int* __restrict__ dst,
    const float* __restrict__ ew, uint2* __restrict__ rec,
    unsigned* __restrict__ cursors) {
    __shared__ unsigned cnt[NB];
    __shared__ unsigned base[NB];
    int tid = threadIdx.x;
    int start = blockIdx.x * CHUNK;
    int end = start + CHUNK;

    for (int i = tid; i < NB; i += 256) cnt[i] = 0;
    __syncthreads();
    for (int i = start + tid; i < end; i += 256) {
        int d = __builtin_nontemporal_load(&dst[i]);
        atomicAdd(&cnt[d >> SBITS], 1u);
    }
    __syncthreads();
    for (int i = tid; i < NB; i += 256) {
        unsigned c = cnt[i];
        base[i] = c ? atomicAdd(&cursors[i], c) : 0u;
    }
    __syncthreads();
    for (int i = tid; i < NB; i += 256) cnt[i] = 0;
    __syncthreads();
    for (int i = start + tid; i < end; i += 256) {
        int d = __builtin_nontemporal_load(&dst[i]);
        int s = __builtin_nontemporal_load(&src[i]);
        float w = __builtin_nontemporal_load(&ew[i]);
        int b = d >> SBITS;
        unsigned p = base[b] + atomicAdd(&cnt[b], 1u);
        unsigned meta = ((unsigned)(d & (S_BUCKET - 1)) << 20) | (unsigned)s;
        rec[p] = make_uint2(meta, __float_as_uint(w));
    }
}

// Exclusive prefix over per-bucket counts -> compact output base per bucket.
__global__ __launch_bounds__(256) void compute_bases(
    const unsigned* __restrict__ cursors, unsigned* __restrict__ bases) {
    __shared__ unsigned c[256];
    int t = threadIdx.x;
    c[t] = (t < NB) ? (cursors[t] - (unsigned)t * CAP) : 0u;
    __syncthreads();
    if (t == 0) {
        unsigned run = 0;
        for (int b = 0; b < NB; ++b) { unsigned v = c[b]; c[b] = run; run += v; }
    }
    __syncthreads();
    if (t < NB) bases[t] = c[t];
}

// Counting-sort each bucket's records by exact dst_local (4096 keys), writing
// (src, weight) records grouped by destination COMPACTLY into rec2 (in d_out),
// and emitting rowstart (index into rec2; rowstart[n+1]-rowstart[n] = degree,
// with a natural sentinel at N_USERS). One block per bucket (round-6 ran 64
// grid-strided blocks -> 2.9% occupancy, 1600us).
__global__ __launch_bounds__(256) void sort_bucket(
    const uint2* __restrict__ rec, const unsigned* __restrict__ cursors,
    const unsigned* __restrict__ bases, uint2* __restrict__ rec2,
    unsigned* __restrict__ rowstart) {
    __shared__ unsigned offs[S_BUCKET];   // histogram -> exclusive offsets
    __shared__ unsigned cnt2[S_BUCKET];
    __shared__ unsigned chunkT[256];
    int tid = threadIdx.x;
    int b = blockIdx.x;

    for (int k = tid; k < S_BUCKET; k += 256) { offs[k] = 0; cnt2[k] = 0; }
    __syncthreads();

    unsigned start = (unsigned)b * CAP;          // even -> 16B-aligned
    unsigned n = cursors[b] - start;
    unsigned gbase = bases[b];                   // compact output base
    const uint2* bp = rec + start;

    // pass A: histogram of dst_local
    unsigned i = 2u * (unsigned)tid;
    for (; i + 2u <= n; i += 512u) {
        uint4v r = __builtin_nontemporal_load(reinterpret_cast<const uint4v*>(bp + i));
        atomicAdd(&offs[r.x >> 20], 1u);
        atomicAdd(&offs[r.z >> 20], 1u);
    }
    if (i < n) {                                  // odd tail (exactly one thread)
        uint2 r = bp[i];
        atomicAdd(&offs[r.x >> 20], 1u);
    }
    __syncthreads();

    // exclusive prefix sum over offs[4096]: 16 cells/thread + serial chunk scan
    {
        int base = tid * 16;
        unsigned run = 0;
        for (int k = 0; k < 16; ++k) { unsigned v = offs[base + k]; offs[base + k] = run; run += v; }
        chunkT[tid] = run;
    }
    __syncthreads();
    if (tid == 0) {
        unsigned run = 0;
        for (int t = 0; t < 256; ++t) { unsigned v = chunkT[t]; chunkT[t] = run; run += v; }
    }
    __syncthreads();
    {
        int base = tid * 16;
        unsigned add = chunkT[tid];
        for (int k = 0; k < 16; ++k) offs[base + k] += add;
    }
    __syncthreads();

    int nb0 = b << SBITS;
    for (int k = tid; k < S_BUCKET; k += 256)
        rowstart[nb0 + k] = gbase + offs[k];

    // pass B: scatter records to exact sorted positions (src, weight)
    i = 2u * (unsigned)tid;
    for (; i + 2u <= n; i += 512u) {
        uint4v r = __builtin_nontemporal_load(reinterpret_cast<const uint4v*>(bp + i));
        unsigned d0 = r.x >> 20, d1 = r.z >> 20;
        unsigned p0 = offs[d0] + atomicAdd(&cnt2[d0], 1u);
        unsigned p1 = offs[d1] + atomicAdd(&cnt2[d1], 1u);
        rec2[gbase + p0] = make_uint2(r.x & 0xFFFFFu, r.y);
        rec2[gbase + p1] = make_uint2(r.z & 0xFFFFFu, r.w);
    }
    if (i < n) {
        uint2 r = bp[i];
        unsigned d0 = r.x >> 20;
        unsigned p0 = offs[d0] + atomicAdd(&cnt2[d0], 1u);
        rec2[gbase + p0] = make_uint2(r.x & 0xFFFFFu, r.y);
    }
}

// Segmented-reduction hop: block owns 256 consecutive nodes = one contiguous
// record range (rows are sorted & contiguous). Stage the range through LDS in
// 16KB chunks with fully-coalesced loads; each thread then reduces its own
// row out of LDS. No atomics anywhere; rec2 lines touched exactly once.
__global__ __launch_bounds__(256) void hop_seg(
    const uint2* __restrict__ rec2, const unsigned* __restrict__ rowstart,
    const float* __restrict__ cur, float* __restrict__ nxt) {
    __shared__ uint2 lds[HOP_CH];
    int tid = threadIdx.x;
    int n0 = blockIdx.x * HOP_NODES;
    int n = n0 + tid;
    int nend = (n0 + HOP_NODES < N_USERS) ? n0 + HOP_NODES : N_USERS;

    unsigned blkS = rowstart[n0];
    unsigned blkE = rowstart[nend];
    unsigned s = (n < N_USERS) ? rowstart[n]     : blkE;
    unsigned e = (n < N_USERS) ? rowstart[n + 1] : blkE;

    float sum = 0.0f;
    for (unsigned cb = blkS; cb < blkE; cb += HOP_CH) {
        unsigned ce = cb + HOP_CH < blkE ? cb + HOP_CH : blkE;
        __syncthreads();                       // previous chunk fully consumed
        for (unsigned i = cb + tid; i < ce; i += 256)
            lds[i - cb] = rec2[i];             // coalesced 8B/lane
        __syncthreads();
        unsigned a  = s > cb ? s : cb;
        unsigned b2 = e < ce ? e : ce;
        for (unsigned p = a; p < b2; ++p) {
            uint2 r = lds[p - cb];
            sum += cur[r.x] * __uint_as_float(r.y);
        }
    }
    if (n < N_USERS) nxt[n] = sum;
}

// ---------------- fallback path (device atomics, small workspace) ----------------

__global__ void zero_kernel(float* __restrict__ p, int n) {
    int i = blockIdx.x * blockDim.x + threadIdx.x;
    int stride = gridDim.x * blockDim.x;
    for (; i < n; i += stride) p[i] = 0.0f;
}

__global__ __launch_bounds__(256) void hop_atomic(
    const int* __restrict__ src, const int* __restrict__ dst,
    const float* __restrict__ ew, const float* __restrict__ cur,
    float* __restrict__ nxt) {
    int e = blockIdx.x * blockDim.x + threadIdx.x;
    if (e * 4 < NEDGE) {
        int4   s = ((const int4*)src)[e];
        int4   d = ((const int4*)dst)[e];
        float4 w = ((const float4*)ew)[e];
        atomicAdd(&nxt[d.x], cur[s.x] * w.x);
        atomicAdd(&nxt[d.y], cur[s.y] * w.y);
        atomicAdd(&nxt[d.z], cur[s.z] * w.z);
        atomicAdd(&nxt[d.w], cur[s.w] * w.w);
    }
}

// ---------------- finalize: 5->64 matvec + BatchNorm over features ----------------

__global__ __launch_bounds__(256) void finalize_kernel(
    const float* __restrict__ x,  const float* __restrict__ f1,
    const float* __restrict__ f2, const float* __restrict__ f3,
    const float* __restrict__ f4, const float* __restrict__ W,
    const float* __restrict__ bias, const float* __restrict__ gamma,
    const float* __restrict__ beta, float* __restrict__ out) {
    int lane = threadIdx.x & 63;
    int waveInBlock = threadIdx.x >> 6;
    int wavesPerBlock = blockDim.x >> 6;
    int gwave  = blockIdx.x * wavesPerBlock + waveInBlock;
    int nwaves = gridDim.x * wavesPerBlock;

    float w0 = W[lane * 5 + 0];
    float w1 = W[lane * 5 + 1];
    float w2 = W[lane * 5 + 2];
    float w3 = W[lane * 5 + 3];
    float w4 = W[lane * 5 + 4];
    float b  = bias[lane];

    for (int n = gwave; n < N_USERS; n += nwaves) {
        float c0 = x[n], c1 = f1[n], c2 = f2[n], c3 = f3[n], c4 = f4[n];
        float y = b + c0 * w0 + c1 * w1 + c2 * w2 + c3 * w3 + c4 * w4;

        float s = y;
        #pragma unroll
        for (int off = 32; off; off >>= 1) s += __shfl_xor(s, off);
        float mean = s * (1.0f / 64.0f);

        float d = y - mean;
        float v = d * d;
        #pragma unroll
        for (int off = 32; off; off >>= 1) v += __shfl_xor(v, off);
        float var = v * (1.0f / 64.0f);

        float o = d * rsqrtf(var + BN_EPS) * gamma[n] + beta[n];
        __builtin_nontemporal_store(o, &out[(size_t)n * OUT_F + lane]);
    }
}

extern "C" void kernel_launch(void* const* d_in, const int* in_sizes, int n_in,
                              void* d_out, int out_size, void* d_ws, size_t ws_size,
                              hipStream_t stream) {
    const float* x     = (const float*)d_in[0];
    const int*   ei    = (const int*)d_in[1];
    const float* ew    = (const float*)d_in[2];
    const float* W     = (const float*)d_in[3];
    const float* bias  = (const float*)d_in[4];
    const float* gamma = (const float*)d_in[5];
    const float* beta  = (const float*)d_in[6];
    float* out = (float*)d_out;

    const int* src = ei;
    const int* dst = ei + NEDGE;

    // Workspace layout (total ~288.4MB; known-available >= 304MB from rounds 0-1)
    float* f = (float*)d_ws;                                   // 16MB
    uint2* rec = (uint2*)(f + 4ull * N_USERS);                 // 268.3MB (padded)
    unsigned* cursors = (unsigned*)(rec + (size_t)NB * CAP);   // 4KB (padded)
    unsigned* bases = cursors + 1024;                          // 4KB (padded)
    unsigned* rowstart = bases + 1024;                         // (NB*S_BUCKET)*4 = 4.01MB
    size_t needed = 16000000ull + (size_t)NB * CAP * 8 + 8192
                  + (size_t)NB * S_BUCKET * 4;

    // Compact sorted record array lives in d_out (dead until finalize).
    uint2* rec2 = (uint2*)d_out;

    if (ws_size >= needed) {
        init_cursors<<<1, 256, 0, stream>>>(cursors);
        scatter_bin<<<SCAT_BLOCKS, 256, 0, stream>>>(src, dst, ew, rec, cursors);
        compute_bases<<<1, 256, 0, stream>>>(cursors, bases);
        sort_bucket<<<NB, 256, 0, stream>>>(rec, cursors, bases, rec2, rowstart);
        const float* cur = x;
        for (int h = 0; h < 4; ++h) {
            float* nxt = f + (size_t)h * N_USERS;
            hop_seg<<<(N_USERS + HOP_NODES - 1) / HOP_NODES, 256, 0, stream>>>(
                rec2, rowstart, cur, nxt);
            cur = nxt;
        }
    } else {
        zero_kernel<<<4096, 256, 0, stream>>>(f, 4 * N_USERS);
        const float* cur = x;
        for (int h = 0; h < 4; ++h) {
            float* nxt = f + (size_t)h * N_USERS;
            hop_atomic<<<NEDGE / 4 / 256, 256, 0, stream>>>(src, dst, ew, cur, nxt);
            cur = nxt;
        }
    }

    finalize_kernel<<<2048, 256, 0, stream>>>(
        x, f, f + N_USERS, f + 2 * N_USERS, f + 3 * N_USERS,
        W, bias, gamma, beta, out);
}

// Round 8
// 2418.858 us; speedup vs baseline: 2.7590x; 1.0811x over previous
//
#include <hip/hip_runtime.h>

#define N_USERS 1000000
#define NEDGE   32000000
#define OUT_F   64
#define BN_EPS  1e-5f

// Destination binning geometry.
// S_BUCKET=4096 is the max where meta packs: dst_local(12b)<<20 | src(20b).
#define SBITS     12
#define S_BUCKET  4096                     // nodes per bucket
#define NB        245                      // ceil(N_USERS / S_BUCKET)
// CAP: mean 130612, sigma ~361; slack ~17 sigma. Padded rec (NB*CAP*8=268.3MB)
// lives in workspace. The SORTED array rec2 is COMPACT (exactly NEDGE*8 =
// 256,000,000 B) and lives in d_out (N_USERS*OUT_F*4 = 256,000,000 B).
// Do NOT gate on the runtime out_size param: its units are not bytes
// (rounds 4-5 silently ran the 6.7ms fallback because of that guard).
#define CAP       136896
#define SCAT_BLOCKS 1024
#define TILE      4096                     // edges per scatter tile (LDS-sorted)
#define NTILES    ((NEDGE + TILE - 1) / TILE)

#define HOP_NODES 256                      // nodes per hop block
#define HOP_CH    2048                     // records per LDS chunk (16KB x 2 buffers)
#define HOP_PF    (HOP_CH / 256)           // prefetch regs per thread

static_assert((unsigned long long)NEDGE * 8ull <=
              (unsigned long long)N_USERS * OUT_F * 4ull,
              "compact rec2 must fit in d_out");

typedef unsigned int uint4v __attribute__((ext_vector_type(4)));  // nontemporal-loadable

// ---------------- binned path ----------------

__global__ void init_cursors(unsigned* __restrict__ cursors) {
    int i = blockIdx.x * blockDim.x + threadIdx.x;
    if (i < NB) cursors[i] = (unsigned)i * CAP;
}

// Tile-sorted scatter: each block takes a 4096-edge tile, counting-sorts it by
// destination bucket ENTIRELY IN LDS, reserves one contiguous global range per
// (tile,bucket) with a single atomicAdd, then flushes coalesced runs (avg
// ~134B contiguous per bucket-segment). Round-7's direct 8B scatter amplified
// writes 3.7x (814MB for 256MB of records); coalesced segment flush avoids it.
__global__ __launch_bounds__(256) void scatter_bin(
    const int* __restrict__ src, const int* __restrict__ dst,
    const float* __restrict__ ew, uint2* __restrict__ rec,
    unsigned* __restrict__ cursors) {
    __shared__ uint2 srec[TILE];             // 32KB tile records, bucket-sorted
    __shared__ unsigned short sbkt[TILE];    // 8KB bucket id per sorted pos
    __shared__ unsigned hist[NB];            // counts -> exclusive seg starts
    __shared__ unsigned curs[NB];            // per-bucket scatter cursor
    __shared__ unsigned gpos[NB];            // absolute global base of segment
    int tid = threadIdx.x;

    for (int tile = blockIdx.x; tile < NTILES; tile += gridDim.x) {
        int e0 = tile * TILE;
        int n_this = (e0 + TILE <= NEDGE) ? TILE : (NEDGE - e0);

        for (int i = tid; i < NB; i += 256) hist[i] = 0;
        __syncthreads();

        int d[16];
        #pragma unroll
        for (int k = 0; k < 16; ++k) {
            int e = e0 + k * 256 + tid;
            if (e < NEDGE) {
                d[k] = __builtin_nontemporal_load(&dst[e]);
                atomicAdd(&hist[d[k] >> SBITS], 1u);
            }
        }
        __syncthreads();

        if (tid == 0) {                       // exclusive scan over 245 buckets
            unsigned run = 0;
            for (int b = 0; b < NB; ++b) { unsigned v = hist[b]; hist[b] = run; run += v; }
        }
        __syncthreads();

        for (int b = tid; b < NB; b += 256) {
            unsigned st = hist[b];
            unsigned en = (b == NB - 1) ? (unsigned)n_this : hist[b + 1];
            unsigned c = en - st;
            gpos[b] = c ? atomicAdd(&cursors[b], c) : 0u;
            curs[b] = 0;
        }
        __syncthreads();

        #pragma unroll
        for (int k = 0; k < 16; ++k) {
            int e = e0 + k * 256 + tid;
            if (e < NEDGE) {
                int dd = d[k];
                int b = dd >> SBITS;
                int s = __builtin_nontemporal_load(&src[e]);
                float w = __builtin_nontemporal_load(&ew[e]);
                unsigned p = hist[b] + atomicAdd(&curs[b], 1u);
                srec[p] = make_uint2(((unsigned)(dd & (S_BUCKET - 1)) << 20) | (unsigned)s,
                                     __float_as_uint(w));
                sbkt[p] = (unsigned short)b;
            }
        }
        __syncthreads();

        for (int i = tid; i < n_this; i += 256) {   // coalesced segment flush
            unsigned b = sbkt[i];
            rec[gpos[b] + ((unsigned)i - hist[b])] = srec[i];
        }
        __syncthreads();                            // before next tile reuses LDS
    }
}

// Exclusive prefix over per-bucket counts -> compact output base per bucket.
__global__ __launch_bounds__(256) void compute_bases(
    const unsigned* __restrict__ cursors, unsigned* __restrict__ bases) {
    __shared__ unsigned c[256];
    int t = threadIdx.x;
    c[t] = (t < NB) ? (cursors[t] - (unsigned)t * CAP) : 0u;
    __syncthreads();
    if (t == 0) {
        unsigned run = 0;
        for (int b = 0; b < NB; ++b) { unsigned v = c[b]; c[b] = run; run += v; }
    }
    __syncthreads();
    if (t < NB) bases[t] = c[t];
}

// Counting-sort each bucket's records by exact dst_local (4096 keys), writing
// (src, weight) records grouped by destination COMPACTLY into rec2 (in d_out),
// and emitting rowstart (rowstart[n+1]-rowstart[n] = degree, natural sentinel).
__global__ __launch_bounds__(256) void sort_bucket(
    const uint2* __restrict__ rec, const unsigned* __restrict__ cursors,
    const unsigned* __restrict__ bases, uint2* __restrict__ rec2,
    unsigned* __restrict__ rowstart) {
    __shared__ unsigned offs[S_BUCKET];   // histogram -> exclusive offsets
    __shared__ unsigned cnt2[S_BUCKET];
    __shared__ unsigned chunkT[256];
    int tid = threadIdx.x;
    int b = blockIdx.x;

    for (int k = tid; k < S_BUCKET; k += 256) { offs[k] = 0; cnt2[k] = 0; }
    __syncthreads();

    unsigned start = (unsigned)b * CAP;          // even -> 16B-aligned
    unsigned n = cursors[b] - start;
    unsigned gbase = bases[b];                   // compact output base
    const uint2* bp = rec + start;

    // pass A: histogram of dst_local
    unsigned i = 2u * (unsigned)tid;
    for (; i + 2u <= n; i += 512u) {
        uint4v r = __builtin_nontemporal_load(reinterpret_cast<const uint4v*>(bp + i));
        atomicAdd(&offs[r.x >> 20], 1u);
        atomicAdd(&offs[r.z >> 20], 1u);
    }
    if (i < n) {                                  // odd tail (exactly one thread)
        uint2 r = bp[i];
        atomicAdd(&offs[r.x >> 20], 1u);
    }
    __syncthreads();

    // exclusive prefix sum over offs[4096]: 16 cells/thread + serial chunk scan
    {
        int base = tid * 16;
        unsigned run = 0;
        for (int k = 0; k < 16; ++k) { unsigned v = offs[base + k]; offs[base + k] = run; run += v; }
        chunkT[tid] = run;
    }
    __syncthreads();
    if (tid == 0) {
        unsigned run = 0;
        for (int t = 0; t < 256; ++t) { unsigned v = chunkT[t]; chunkT[t] = run; run += v; }
    }
    __syncthreads();
    {
        int base = tid * 16;
        unsigned add = chunkT[tid];
        for (int k = 0; k < 16; ++k) offs[base + k] += add;
    }
    __syncthreads();

    int nb0 = b << SBITS;
    for (int k = tid; k < S_BUCKET; k += 256)
        rowstart[nb0 + k] = gbase + offs[k];

    // pass B: scatter records to exact sorted positions (src, weight)
    i = 2u * (unsigned)tid;
    for (; i + 2u <= n; i += 512u) {
        uint4v r = __builtin_nontemporal_load(reinterpret_cast<const uint4v*>(bp + i));
        unsigned d0 = r.x >> 20, d1 = r.z >> 20;
        unsigned p0 = offs[d0] + atomicAdd(&cnt2[d0], 1u);
        unsigned p1 = offs[d1] + atomicAdd(&cnt2[d1], 1u);
        rec2[gbase + p0] = make_uint2(r.x & 0xFFFFFu, r.y);
        rec2[gbase + p1] = make_uint2(r.z & 0xFFFFFu, r.w);
    }
    if (i < n) {
        uint2 r = bp[i];
        unsigned d0 = r.x >> 20;
        unsigned p0 = offs[d0] + atomicAdd(&cnt2[d0], 1u);
        rec2[gbase + p0] = make_uint2(r.x & 0xFFFFFu, r.y);
    }
}

// Segmented-reduction hop, double-buffered: while consuming chunk k from LDS,
// chunk k+1 is prefetched into registers (global latency hidden under the
// consume phase). Consume is 4-way unrolled with 4 independent accumulators so
// 4 xin gathers are in flight per lane (round-7 had 1 -> latency-serialized).
__global__ __launch_bounds__(256) void hop_seg(
    const uint2* __restrict__ rec2, const unsigned* __restrict__ rowstart,
    const float* __restrict__ xin, float* __restrict__ nxt) {
    __shared__ uint2 lds[2][HOP_CH];
    int tid = threadIdx.x;
    int n0 = blockIdx.x * HOP_NODES;
    int n = n0 + tid;
    int nend = (n0 + HOP_NODES < N_USERS) ? n0 + HOP_NODES : N_USERS;

    unsigned blkS = rowstart[n0];
    unsigned blkE = rowstart[nend];
    unsigned s = (n < N_USERS) ? rowstart[n]     : blkE;
    unsigned e = (n < N_USERS) ? rowstart[n + 1] : blkE;

    // prologue: stage chunk 0 into buffer 0
    {
        unsigned ce = blkS + HOP_CH < blkE ? blkS + HOP_CH : blkE;
        for (unsigned i = blkS + tid; i < ce; i += 256)
            lds[0][i - blkS] = rec2[i];
    }
    int cur = 0;
    float s0 = 0, s1 = 0, s2 = 0, s3 = 0;

    for (unsigned cb = blkS; cb < blkE; cb += HOP_CH) {
        unsigned ce = cb + HOP_CH < blkE ? cb + HOP_CH : blkE;
        __syncthreads();   // lds[cur] staged; lds[cur^1] fully consumed (prev iter)

        // prefetch next chunk into registers (no barrier needed until write)
        unsigned nb = cb + HOP_CH;
        unsigned ne2 = nb + HOP_CH < blkE ? nb + HOP_CH : blkE;
        uint2 pf[HOP_PF];
        bool pfv[HOP_PF];
        bool have_next = nb < blkE;
        if (have_next) {
            #pragma unroll
            for (int k = 0; k < HOP_PF; ++k) {
                unsigned i = nb + (unsigned)tid + (unsigned)k * 256u;
                pfv[k] = (i < ne2);
                if (pfv[k]) pf[k] = rec2[i];
            }
        }

        // consume own row's slice of this chunk
        unsigned a  = s > cb ? s : cb;
        unsigned b2 = e < ce ? e : ce;
        unsigned p = a;
        for (; p + 4 <= b2; p += 4) {
            uint2 r0 = lds[cur][p - cb];
            uint2 r1 = lds[cur][p + 1 - cb];
            uint2 r2 = lds[cur][p + 2 - cb];
            uint2 r3 = lds[cur][p + 3 - cb];
            s0 += xin[r0.x] * __uint_as_float(r0.y);
            s1 += xin[r1.x] * __uint_as_float(r1.y);
            s2 += xin[r2.x] * __uint_as_float(r2.y);
            s3 += xin[r3.x] * __uint_as_float(r3.y);
        }
        for (; p < b2; ++p) {
            uint2 r = lds[cur][p - cb];
            s0 += xin[r.x] * __uint_as_float(r.y);
        }

        // write prefetched chunk into the other buffer
        if (have_next) {
            #pragma unroll
            for (int k = 0; k < HOP_PF; ++k)
                if (pfv[k]) lds[cur ^ 1][tid + k * 256] = pf[k];
        }
        cur ^= 1;
    }
    if (n < N_USERS) nxt[n] = (s0 + s1) + (s2 + s3);
}

// ---------------- fallback path (device atomics, small workspace) ----------------

__global__ void zero_kernel(float* __restrict__ p, int n) {
    int i = blockIdx.x * blockDim.x + threadIdx.x;
    int stride = gridDim.x * blockDim.x;
    for (; i < n; i += stride) p[i] = 0.0f;
}

__global__ __launch_bounds__(256) void hop_atomic(
    const int* __restrict__ src, const int* __restrict__ dst,
    const float* __restrict__ ew, const float* __restrict__ cur,
    float* __restrict__ nxt) {
    int e = blockIdx.x * blockDim.x + threadIdx.x;
    if (e * 4 < NEDGE) {
        int4   s = ((const int4*)src)[e];
        int4   d = ((const int4*)dst)[e];
        float4 w = ((const float4*)ew)[e];
        atomicAdd(&nxt[d.x], cur[s.x] * w.x);
        atomicAdd(&nxt[d.y], cur[s.y] * w.y);
        atomicAdd(&nxt[d.z], cur[s.z] * w.z);
        atomicAdd(&nxt[d.w], cur[s.w] * w.w);
    }
}

// ---------------- finalize: 5->64 matvec + BatchNorm over features ----------------

__global__ __launch_bounds__(256) void finalize_kernel(
    const float* __restrict__ x,  const float* __restrict__ f1,
    const float* __restrict__ f2, const float* __restrict__ f3,
    const float* __restrict__ f4, const float* __restrict__ W,
    const float* __restrict__ bias, const float* __restrict__ gamma,
    const float* __restrict__ beta, float* __restrict__ out) {
    int lane = threadIdx.x & 63;
    int waveInBlock = threadIdx.x >> 6;
    int wavesPerBlock = blockDim.x >> 6;
    int gwave  = blockIdx.x * wavesPerBlock + waveInBlock;
    int nwaves = gridDim.x * wavesPerBlock;

    float w0 = W[lane * 5 + 0];
    float w1 = W[lane * 5 + 1];
    float w2 = W[lane * 5 + 2];
    float w3 = W[lane * 5 + 3];
    float w4 = W[lane * 5 + 4];
    float b  = bias[lane];

    for (int n = gwave; n < N_USERS; n += nwaves) {
        float c0 = x[n], c1 = f1[n], c2 = f2[n], c3 = f3[n], c4 = f4[n];
        float y = b + c0 * w0 + c1 * w1 + c2 * w2 + c3 * w3 + c4 * w4;

        float s = y;
        #pragma unroll
        for (int off = 32; off; off >>= 1) s += __shfl_xor(s, off);
        float mean = s * (1.0f / 64.0f);

        float d = y - mean;
        float v = d * d;
        #pragma unroll
        for (int off = 32; off; off >>= 1) v += __shfl_xor(v, off);
        float var = v * (1.0f / 64.0f);

        float o = d * rsqrtf(var + BN_EPS) * gamma[n] + beta[n];
        __builtin_nontemporal_store(o, &out[(size_t)n * OUT_F + lane]);
    }
}

extern "C" void kernel_launch(void* const* d_in, const int* in_sizes, int n_in,
                              void* d_out, int out_size, void* d_ws, size_t ws_size,
                              hipStream_t stream) {
    const float* x     = (const float*)d_in[0];
    const int*   ei    = (const int*)d_in[1];
    const float* ew    = (const float*)d_in[2];
    const float* W     = (const float*)d_in[3];
    const float* bias  = (const float*)d_in[4];
    const float* gamma = (const float*)d_in[5];
    const float* beta  = (const float*)d_in[6];
    float* out = (float*)d_out;

    const int* src = ei;
    const int* dst = ei + NEDGE;

    // Workspace layout (total ~288.4MB; known-available >= 304MB from rounds 0-1)
    float* f = (float*)d_ws;                                   // 16MB
    uint2* rec = (uint2*)(f + 4ull * N_USERS);                 // 268.3MB (padded)
    unsigned* cursors = (unsigned*)(rec + (size_t)NB * CAP);   // 4KB (padded)
    unsigned* bases = cursors + 1024;                          // 4KB (padded)
    unsigned* rowstart = bases + 1024;                         // (NB*S_BUCKET)*4 = 4.01MB
    size_t needed = 16000000ull + (size_t)NB * CAP * 8 + 8192
                  + (size_t)NB * S_BUCKET * 4;

    // Compact sorted record array lives in d_out (dead until finalize).
    uint2* rec2 = (uint2*)d_out;

    if (ws_size >= needed) {
        init_cursors<<<1, 256, 0, stream>>>(cursors);
        scatter_bin<<<SCAT_BLOCKS, 256, 0, stream>>>(src, dst, ew, rec, cursors);
        compute_bases<<<1, 256, 0, stream>>>(cursors, bases);
        sort_bucket<<<NB, 256, 0, stream>>>(rec, cursors, bases, rec2, rowstart);
        const float* cur = x;
        for (int h = 0; h < 4; ++h) {
            float* nxt = f + (size_t)h * N_USERS;
            hop_seg<<<(N_USERS + HOP_NODES - 1) / HOP_NODES, 256, 0, stream>>>(
                rec2, rowstart, cur, nxt);
            cur = nxt;
        }
    } else {
        zero_kernel<<<4096, 256, 0, stream>>>(f, 4 * N_USERS);
        const float* cur = x;
        for (int h = 0; h < 4; ++h) {
            float* nxt = f + (size_t)h * N_USERS;
            hop_atomic<<<NEDGE / 4 / 256, 256, 0, stream>>>(src, dst, ew, cur, nxt);
            cur = nxt;
        }
    }

    finalize_kernel<<<2048, 256, 0, stream>>>(
        x, f, f + N_USERS, f + 2 * N_USERS, f + 3 * N_USERS,
        W, bias, gamma, beta, out);
}

// Round 9
// 1781.381 us; speedup vs baseline: 3.7463x; 1.3579x over previous
//
#include <hip/hip_runtime.h>

#define N_USERS 1000000
#define NEDGE   32000000
#define OUT_F   64
#define BN_EPS  1e-5f

// Destination binning geometry.
// S_BUCKET=4096 is the max where meta packs: dst_local(12b)<<20 | src(20b).
#define SBITS     12
#define S_BUCKET  4096                     // nodes per bucket
#define NB        245                      // ceil(N_USERS / S_BUCKET)
// CAP: mean 130612, sigma ~361; slack ~17 sigma.
#define CAP       136896
#define SCAT_BLOCKS 1024
#define TILE      4096                     // edges per scatter tile (LDS-sorted)
#define NTILES    ((NEDGE + TILE - 1) / TILE)
#define SPLIT     8                        // blocks per bucket in the hop kernel

typedef unsigned int uint4v __attribute__((ext_vector_type(4)));  // nontemporal-loadable

// ---------------- binned path ----------------

__global__ void init_cursors(unsigned* __restrict__ cursors) {
    int i = blockIdx.x * blockDim.x + threadIdx.x;
    if (i < NB) cursors[i] = (unsigned)i * CAP;
}

// Tile-sorted scatter: each block takes a 4096-edge tile, counting-sorts it by
// destination bucket ENTIRELY IN LDS, reserves one contiguous global range per
// (tile,bucket) with a single atomicAdd, then flushes coalesced runs.
__global__ __launch_bounds__(256) void scatter_bin(
    const int* __restrict__ src, const int* __restrict__ dst,
    const float* __restrict__ ew, uint2* __restrict__ rec,
    unsigned* __restrict__ cursors) {
    __shared__ uint2 srec[TILE];             // 32KB tile records, bucket-sorted
    __shared__ unsigned short sbkt[TILE];    // 8KB bucket id per sorted pos
    __shared__ unsigned hist[NB];            // counts -> exclusive seg starts
    __shared__ unsigned curs[NB];            // per-bucket scatter cursor
    __shared__ unsigned gpos[NB];            // absolute global base of segment
    int tid = threadIdx.x;

    for (int tile = blockIdx.x; tile < NTILES; tile += gridDim.x) {
        int e0 = tile * TILE;
        int n_this = (e0 + TILE <= NEDGE) ? TILE : (NEDGE - e0);

        for (int i = tid; i < NB; i += 256) hist[i] = 0;
        __syncthreads();

        int d[16];
        #pragma unroll
        for (int k = 0; k < 16; ++k) {
            int e = e0 + k * 256 + tid;
            if (e < NEDGE) {
                d[k] = __builtin_nontemporal_load(&dst[e]);
                atomicAdd(&hist[d[k] >> SBITS], 1u);
            }
        }
        __syncthreads();

        if (tid == 0) {                       // exclusive scan over 245 buckets
            unsigned run = 0;
            for (int b = 0; b < NB; ++b) { unsigned v = hist[b]; hist[b] = run; run += v; }
        }
        __syncthreads();

        for (int b = tid; b < NB; b += 256) {
            unsigned st = hist[b];
            unsigned en = (b == NB - 1) ? (unsigned)n_this : hist[b + 1];
            unsigned c = en - st;
            gpos[b] = c ? atomicAdd(&cursors[b], c) : 0u;
            curs[b] = 0;
        }
        __syncthreads();

        #pragma unroll
        for (int k = 0; k < 16; ++k) {
            int e = e0 + k * 256 + tid;
            if (e < NEDGE) {
                int dd = d[k];
                int b = dd >> SBITS;
                int s = __builtin_nontemporal_load(&src[e]);
                float w = __builtin_nontemporal_load(&ew[e]);
                unsigned p = hist[b] + atomicAdd(&curs[b], 1u);
                srec[p] = make_uint2(((unsigned)(dd & (S_BUCKET - 1)) << 20) | (unsigned)s,
                                     __float_as_uint(w));
                sbkt[p] = (unsigned short)b;
            }
        }
        __syncthreads();

        for (int i = tid; i < n_this; i += 256) {   // coalesced segment flush
            unsigned b = sbkt[i];
            rec[gpos[b] + ((unsigned)i - hist[b])] = srec[i];
        }
        __syncthreads();                            // before next tile reuses LDS
    }
}

// LDS-accumulation hop, no sort stage needed: SPLIT blocks per 4096-node
// bucket, each streams its slice of the bucket's records (nt loads: read-once
// stream must not evict cur[] from L2), gathers cur[src], and ds_add_f32 into
// a 16KB accumulator. ds_add is fire-and-forget (no return) so the only
// latency to hide is the gather; 4 records/iter keep 4 gathers in flight.
// Flush is one coalesced global atomicAdd pass (nxt pre-zeroed).
__global__ __launch_bounds__(256) void hop_bucket(
    const uint2* __restrict__ rec, const unsigned* __restrict__ cursors,
    const float* __restrict__ cur, float* __restrict__ nxt) {
    __shared__ float acc[S_BUCKET];
    int tid = threadIdx.x;
    int b = blockIdx.x / SPLIT;
    int sidx = blockIdx.x % SPLIT;
    for (int i = tid; i < S_BUCKET; i += 256) acc[i] = 0.0f;
    __syncthreads();

    unsigned start = (unsigned)b * CAP;          // CAP mult of 4 -> 32B aligned
    unsigned cnt = cursors[b] - start;
    unsigned u0 = ((cnt * (unsigned)sidx) / SPLIT) & ~3u;
    unsigned u1 = (sidx == SPLIT - 1) ? cnt : (((cnt * (unsigned)(sidx + 1)) / SPLIT) & ~3u);
    const uint2* bp = rec + start;

    unsigned i = u0 + 4u * (unsigned)tid;
    for (; i + 4u <= u1; i += 4u * 256u) {
        uint4v r0 = __builtin_nontemporal_load(reinterpret_cast<const uint4v*>(bp + i));
        uint4v r1 = __builtin_nontemporal_load(reinterpret_cast<const uint4v*>(bp + i + 2));
        float c0 = cur[r0.x & 0xFFFFFu];
        float c1 = cur[r0.z & 0xFFFFFu];
        float c2 = cur[r1.x & 0xFFFFFu];
        float c3 = cur[r1.z & 0xFFFFFu];
        atomicAdd(&acc[r0.x >> 20], c0 * __uint_as_float(r0.y));
        atomicAdd(&acc[r0.z >> 20], c1 * __uint_as_float(r0.w));
        atomicAdd(&acc[r1.x >> 20], c2 * __uint_as_float(r1.y));
        atomicAdd(&acc[r1.z >> 20], c3 * __uint_as_float(r1.w));
    }
    if (i < u1) {                                // at most one straddling quad
        for (unsigned j = i; j < i + 4u && j < u1; ++j) {
            uint2 r = bp[j];
            atomicAdd(&acc[r.x >> 20], cur[r.x & 0xFFFFFu] * __uint_as_float(r.y));
        }
    }
    __syncthreads();

    int nb0 = b << SBITS;
    for (int k = tid; k < S_BUCKET; k += 256) {
        int n = nb0 + k;
        if (n < N_USERS) atomicAdd(&nxt[n], acc[k]);
    }
}

// ---------------- fallback path (device atomics, small workspace) ----------------

__global__ void zero_kernel(float* __restrict__ p, int n) {
    int i = blockIdx.x * blockDim.x + threadIdx.x;
    int stride = gridDim.x * blockDim.x;
    for (; i < n; i += stride) p[i] = 0.0f;
}

__global__ __launch_bounds__(256) void hop_atomic(
    const int* __restrict__ src, const int* __restrict__ dst,
    const float* __restrict__ ew, const float* __restrict__ cur,
    float* __restrict__ nxt) {
    int e = blockIdx.x * blockDim.x + threadIdx.x;
    if (e * 4 < NEDGE) {
        int4   s = ((const int4*)src)[e];
        int4   d = ((const int4*)dst)[e];
        float4 w = ((const float4*)ew)[e];
        atomicAdd(&nxt[d.x], cur[s.x] * w.x);
        atomicAdd(&nxt[d.y], cur[s.y] * w.y);
        atomicAdd(&nxt[d.z], cur[s.z] * w.z);
        atomicAdd(&nxt[d.w], cur[s.w] * w.w);
    }
}

// ---------------- finalize: 5->64 matvec + BatchNorm over features ----------------

__global__ __launch_bounds__(256) void finalize_kernel(
    const float* __restrict__ x,  const float* __restrict__ f1,
    const float* __restrict__ f2, const float* __restrict__ f3,
    const float* __restrict__ f4, const float* __restrict__ W,
    const float* __restrict__ bias, const float* __restrict__ gamma,
    const float* __restrict__ beta, float* __restrict__ out) {
    int lane = threadIdx.x & 63;
    int waveInBlock = threadIdx.x >> 6;
    int wavesPerBlock = blockDim.x >> 6;
    int gwave  = blockIdx.x * wavesPerBlock + waveInBlock;
    int nwaves = gridDim.x * wavesPerBlock;

    float w0 = W[lane * 5 + 0];
    float w1 = W[lane * 5 + 1];
    float w2 = W[lane * 5 + 2];
    float w3 = W[lane * 5 + 3];
    float w4 = W[lane * 5 + 4];
    float b  = bias[lane];

    for (int n = gwave; n < N_USERS; n += nwaves) {
        float c0 = x[n], c1 = f1[n], c2 = f2[n], c3 = f3[n], c4 = f4[n];
        float y = b + c0 * w0 + c1 * w1 + c2 * w2 + c3 * w3 + c4 * w4;

        float s = y;
        #pragma unroll
        for (int off = 32; off; off >>= 1) s += __shfl_xor(s, off);
        float mean = s * (1.0f / 64.0f);

        float d = y - mean;
        float v = d * d;
        #pragma unroll
        for (int off = 32; off; off >>= 1) v += __shfl_xor(v, off);
        float var = v * (1.0f / 64.0f);

        float o = d * rsqrtf(var + BN_EPS) * gamma[n] + beta[n];
        __builtin_nontemporal_store(o, &out[(size_t)n * OUT_F + lane]);
    }
}

extern "C" void kernel_launch(void* const* d_in, const int* in_sizes, int n_in,
                              void* d_out, int out_size, void* d_ws, size_t ws_size,
                              hipStream_t stream) {
    const float* x     = (const float*)d_in[0];
    const int*   ei    = (const int*)d_in[1];
    const float* ew    = (const float*)d_in[2];
    const float* W     = (const float*)d_in[3];
    const float* bias  = (const float*)d_in[4];
    const float* gamma = (const float*)d_in[5];
    const float* beta  = (const float*)d_in[6];
    float* out = (float*)d_out;

    const int* src = ei;
    const int* dst = ei + NEDGE;

    // Workspace layout (total ~284.4MB; known-available >= 304MB from rounds 0-1)
    float* f = (float*)d_ws;                                   // 16MB
    uint2* rec = (uint2*)(f + 4ull * N_USERS);                 // 268.3MB (padded)
    unsigned* cursors = (unsigned*)(rec + (size_t)NB * CAP);   // 4KB (padded)
    size_t needed = 16000000ull + (size_t)NB * CAP * 8 + 4096;

    if (ws_size >= needed) {
        init_cursors<<<1, 256, 0, stream>>>(cursors);
        zero_kernel<<<2048, 256, 0, stream>>>(f, 4 * N_USERS);   // hop flush is atomicAdd
        scatter_bin<<<SCAT_BLOCKS, 256, 0, stream>>>(src, dst, ew, rec, cursors);
        const float* cur = x;
        for (int h = 0; h < 4; ++h) {
            float* nxt = f + (size_t)h * N_USERS;
            hop_bucket<<<NB * SPLIT, 256, 0, stream>>>(rec, cursors, cur, nxt);
            cur = nxt;
        }
    } else {
        zero_kernel<<<4096, 256, 0, stream>>>(f, 4 * N_USERS);
        const float* cur = x;
        for (int h = 0; h < 4; ++h) {
            float* nxt = f + (size_t)h * N_USERS;
            hop_atomic<<<NEDGE / 4 / 256, 256, 0, stream>>>(src, dst, ew, cur, nxt);
            cur = nxt;
        }
    }

    finalize_kernel<<<2048, 256, 0, stream>>>(
        x, f, f + N_USERS, f + 2 * N_USERS, f + 3 * N_USERS,
        W, bias, gamma, beta, out);
}